// Round 1
// 2064.929 us; speedup vs baseline: 1.2260x; 1.2260x over previous
//
#include <hip/hip_runtime.h>
#include <hip/hip_bf16.h>

#define TT 2048
#define BB 256
#define II 64
#define HH 128
#define GG 512   // 4*H
#define NHH 512
#define OO 64

#define OSTRIDE 516   // shorts/row: dword-stride 258 %32 = 2 -> b64 reads at conflict floor

typedef short short8 __attribute__((ext_vector_type(8)));
typedef short short4v __attribute__((ext_vector_type(4)));
typedef float f32x4 __attribute__((ext_vector_type(4)));
typedef unsigned short us4 __attribute__((ext_vector_type(4)));

__device__ __forceinline__ short f2bf(float f) {
    unsigned u = __float_as_uint(f);
    unsigned r = (u + 0x7fffu + ((u >> 16) & 1u)) >> 16;   // RNE
    return (short)r;
}
__device__ __forceinline__ float bf2f(unsigned short s) {
    return __uint_as_float(((unsigned)s) << 16);
}
__device__ __forceinline__ float sigm(float x) {
    return __builtin_amdgcn_rcpf(1.f + __expf(-x));
}
__device__ __forceinline__ float tanh_f(float x) {
    float e = __expf(-2.f * fabsf(x));
    float t = (1.f - e) * __builtin_amdgcn_rcpf(1.f + e);
    return copysignf(t, x);
}
// LDS-only barrier: waits lgkmcnt(0) but NOT vmcnt -> no HBM-store drain per step
__device__ __forceinline__ void sync_lds() {
    __builtin_amdgcn_s_waitcnt(0xC07F);
    __builtin_amdgcn_s_barrier();
}

// ---------- prep: bf16 conversions for the head weights ----------
__global__ void prep_kernel(const float* __restrict__ W1, const float* __restrict__ W2,
                            short* __restrict__ W1bf, short* __restrict__ W2bf)
{
    int tid = blockIdx.x * blockDim.x + threadIdx.x;
    int n = gridDim.x * blockDim.x;
    for (int i = tid; i < NHH * HH; i += n) W1bf[i] = f2bf(W1[i]);
    for (int i = tid; i < OO * NHH; i += n) W2bf[i] = f2bf(W2[i]);
}

// ---------- LSTM scan: 256 blocks x 1 batch row, 8 waves, gate-interleaved MFMA ----------
// Wave wv owns h-cols [wv*16, wv*16+16); its 4 N-tiles are the 4 GATES of that slice
// (W rows g*128 + wv*16 + lrow). After MFMA, lane l<16 holds {i,f,g,o} for col wv*16+l
// in C[0..3][0] -> activations fully in-register, NO gate LDS round-trip, ONE barrier/step.
// A-operand: row 0 = h_t (bf16, broadcast ds_read from 128-short buffer) | x_t (64 bf16).
// Rows 1-15 of A/C are don't-care (row 0 of D depends only on row 0 of A and C).
__global__ __launch_bounds__(512, 2) void lstm_scan6(
    const float* __restrict__ x,
    const float* __restrict__ W_ih, const float* __restrict__ W_hh,
    const float* __restrict__ b_ih, const float* __restrict__ b_hh,
    unsigned short* __restrict__ hs, float* __restrict__ out_tail)
{
    __shared__ __align__(16) short hbuf[2][HH];   // h_t bf16, double-buffered (read t&1, write (t+1)&1)
    __shared__ __align__(16) short xbuf[2][II];   // x_t bf16, double-buffered

    const int tid  = threadIdx.x;
    const int wv   = tid >> 6;            // 8 waves
    const int lane = tid & 63;
    const int lrow = lane & 15;
    const int q    = lane >> 4;
    const int b    = blockIdx.x;          // one batch row per block
    const int col  = wv * 16 + lrow;      // this lane's h-column (lanes<16 only)

    if (tid < 2 * HH) ((short*)hbuf)[tid] = 0;    // h_{-1} = 0 (both buffers)

    // B-frags: gate g, cols [wv*16, wv*16+16), K = [h(128) | x(64)] = 6 k-tiles of 32
    short8 Bf[4][6];
    float biasv[4];
    #pragma unroll
    for (int g = 0; g < 4; ++g) {
        int n = g * 128 + wv * 16 + lrow;         // gate pre-act index = W row
        biasv[g] = b_ih[n] + b_hh[n];
        #pragma unroll
        for (int kt = 0; kt < 6; ++kt) {
            const float* p = (kt < 4) ? (W_hh + (size_t)n * HH + kt * 32 + q * 8)
                                      : (W_ih + (size_t)n * II + (kt - 4) * 32 + q * 8);
            float4 f0 = *(const float4*)p;
            float4 f1 = *(const float4*)(p + 4);
            short8 bb;
            bb[0] = f2bf(f0.x); bb[1] = f2bf(f0.y); bb[2] = f2bf(f0.z); bb[3] = f2bf(f0.w);
            bb[4] = f2bf(f1.x); bb[5] = f2bf(f1.y); bb[6] = f2bf(f1.z); bb[7] = f2bf(f1.w);
            Bf[g][kt] = bb;
        }
    }

    // x staging: wave 0 (tid<64) stages x[t][b][tid]; 2-step-deep register prefetch,
    // t-loop unrolled x2 so xa/xb alternate (no rotation mov, load->use gap = 2 steps)
    float xa = 0.f, xb_r = 0.f;
    if (tid < II) {
        xbuf[0][tid] = f2bf(x[(size_t)b * II + tid]);              // x_0
        xa   = x[(size_t)1 * BB * II + (size_t)b * II + tid];      // x_1
        xb_r = x[(size_t)2 * BB * II + (size_t)b * II + tid];      // x_2
    }
    const float* xp = x + (size_t)3 * BB * II + (size_t)b * II + tid;

    float c = 0.f, hlast = 0.f;
    unsigned short* hp = hs + (size_t)b * HH + col;

    __syncthreads();   // full sync once: LDS init visible + startup vmem drained

    auto step = [&](int t, int par, float& xreg) {
        const short* hb = hbuf[par];
        const short* xbp = xbuf[par];
        // A-frags, broadcast (16 lanes per address -> conflict-free)
        short8 Af[6];
        #pragma unroll
        for (int kt = 0; kt < 4; ++kt)
            Af[kt] = *(const short8*)&hb[kt * 32 + q * 8];
        Af[4] = *(const short8*)&xbp[q * 8];
        Af[5] = *(const short8*)&xbp[32 + q * 8];

        // stage x_{t+1} into the other buffer, refill xreg with x_{t+3}
        if (tid < II) {
            xbuf[par ^ 1][tid] = f2bf(xreg);
            xreg = (t + 3 < TT) ? *xp : 0.f;
            xp += BB * II;
        }

        // gate pre-acts: split accumulators to halve the dependent-MFMA chain
        f32x4 Ca[4], Cb[4];
        #pragma unroll
        for (int g = 0; g < 4; ++g) {
            f32x4 ci = {biasv[g], biasv[g], biasv[g], biasv[g]};
            Ca[g] = ci;
            f32x4 z = {0.f, 0.f, 0.f, 0.f};
            Cb[g] = z;
        }
        #pragma unroll
        for (int kt = 0; kt < 3; ++kt)
            #pragma unroll
            for (int g = 0; g < 4; ++g)
                Ca[g] = __builtin_amdgcn_mfma_f32_16x16x32_bf16(Af[kt], Bf[g][kt], Ca[g], 0, 0, 0);
        #pragma unroll
        for (int kt = 3; kt < 6; ++kt)
            #pragma unroll
            for (int g = 0; g < 4; ++g)
                Cb[g] = __builtin_amdgcn_mfma_f32_16x16x32_bf16(Af[kt], Bf[g][kt], Cb[g], 0, 0, 0);

        // in-register activations: lane l<16 holds {i,f,g,o} of col wv*16+l at reg 0
        if (lane < 16) {
            float gi = Ca[0][0] + Cb[0][0];
            float gf = Ca[1][0] + Cb[1][0];
            float gg = Ca[2][0] + Cb[2][0];
            float go = Ca[3][0] + Cb[3][0];
            c = sigm(gf) * c + sigm(gi) * tanh_f(gg);
            float h = sigm(go) * tanh_f(c);
            hlast = h;
            unsigned short hbb = (unsigned short)f2bf(h);
            hbuf[par ^ 1][col] = (short)hbb;
            *hp = hbb;
        }
        hp += (size_t)BB * HH;
        sync_lds();   // h_{t+1} (and x_{t+1}) visible; single barrier per step
    };

    for (int t = 0; t < TT; t += 2) {
        step(t, 0, xa);
        step(t + 1, 1, xb_r);
    }

    if (lane < 16) {
        out_tail[(size_t)b * HH + col] = hlast;
        out_tail[(size_t)BB * HH + (size_t)b * HH + col] = c;
    }
}

// ---------- fused head MLP, 8 waves, direct-global A-frags ----------
__global__ __launch_bounds__(512) void head_mfma(
    const unsigned short* __restrict__ hs,
    const short* __restrict__ W1bf, const float* __restrict__ b1,
    const short* __restrict__ W2bf, const float* __restrict__ b2,
    float* __restrict__ out)
{
    __shared__ short o1[32 * OSTRIDE];

    const int tid = threadIdx.x, wv = tid >> 6, lane = tid & 63;
    const int lrow = lane & 15, q = lane >> 4;
    const size_t rows0 = (size_t)blockIdx.x * 32;

    // GEMM1: wave -> (mt = wv&1 row-half, nb = (wv>>1)*128 col slice)
    const int mt = wv & 1;
    const int nb = (wv >> 1) * 128;
    f32x4 C1[8];
    #pragma unroll
    for (int nt = 0; nt < 8; ++nt) {
        float bv = b1[nb + nt * 16 + lrow];
        f32x4 ci = {bv, bv, bv, bv};
        C1[nt] = ci;
    }
    #pragma unroll
    for (int kt = 0; kt < 4; ++kt) {
        short8 Af = *(const short8*)(hs + (rows0 + mt * 16 + lrow) * HH + kt * 32 + q * 8);
        #pragma unroll
        for (int nt = 0; nt < 8; ++nt) {
            short8 Bfr = *(const short8*)&W1bf[(nb + nt * 16 + lrow) * HH + kt * 32 + q * 8];
            C1[nt] = __builtin_amdgcn_mfma_f32_16x16x32_bf16(Af, Bfr, C1[nt], 0, 0, 0);
        }
    }
    #pragma unroll
    for (int nt = 0; nt < 8; ++nt) {
        #pragma unroll
        for (int reg = 0; reg < 4; ++reg) {
            float v = C1[nt][reg];
            v = v > 0.f ? v : 0.f;
            o1[(mt * 16 + q * 4 + reg) * OSTRIDE + nb + nt * 16 + lrow] = f2bf(v);
        }
    }
    __syncthreads();

    // GEMM2: wave -> (mt2 row-half, nh = wv>>1 col tile of 16)
    const int mt2 = wv & 1;
    const int nh  = wv >> 1;
    f32x4 C2;
    {
        float bv = b2[nh * 16 + lrow];
        f32x4 ci = {bv, bv, bv, bv};
        C2 = ci;
    }
    #pragma unroll
    for (int kt = 0; kt < 16; ++kt) {
        int off = (mt2 * 16 + lrow) * OSTRIDE + kt * 32 + q * 8;
        union { short8 v; short4v h[2]; } u;
        u.h[0] = *(const short4v*)&o1[off];
        u.h[1] = *(const short4v*)&o1[off + 4];
        short8 Bfr = *(const short8*)&W2bf[(nh * 16 + lrow) * NHH + kt * 32 + q * 8];
        C2 = __builtin_amdgcn_mfma_f32_16x16x32_bf16(u.v, Bfr, C2, 0, 0, 0);
    }
    #pragma unroll
    for (int reg = 0; reg < 4; ++reg)
        out[(rows0 + mt2 * 16 + q * 4 + reg) * OO + nh * 16 + lrow] = C2[reg];
}

extern "C" void kernel_launch(void* const* d_in, const int* in_sizes, int n_in,
                              void* d_out, int out_size, void* d_ws, size_t ws_size,
                              hipStream_t stream)
{
    const float* x    = (const float*)d_in[0];
    const float* W_ih = (const float*)d_in[1];
    const float* W_hh = (const float*)d_in[2];
    const float* b_ih = (const float*)d_in[3];
    const float* b_hh = (const float*)d_in[4];
    const float* W1   = (const float*)d_in[5];
    const float* b1   = (const float*)d_in[6];
    const float* W2   = (const float*)d_in[7];
    const float* b2   = (const float*)d_in[8];
    float* out = (float*)d_out;

    char* ws = (char*)d_ws;
    short* W1bf = (short*)(ws + 0);                        // 131072
    short* W2bf = (short*)(ws + 131072);                   // 65536
    unsigned short* hs = (unsigned short*)(ws + 196608);   // 134217728

    prep_kernel<<<64, 256, 0, stream>>>(W1, W2, W1bf, W2bf);

    float* tail = out + (size_t)TT * BB * OO;
    lstm_scan6<<<BB, 512, 0, stream>>>(x, W_ih, W_hh, b_ih, b_hh, hs, tail);

    head_mfma<<<(TT * BB) / 32, 512, 0, stream>>>(hs, W1bf, b1, W2bf, b2, out);
}

// Round 2
// 1799.076 us; speedup vs baseline: 1.4072x; 1.1478x over previous
//
#include <hip/hip_runtime.h>
#include <hip/hip_bf16.h>

#define TT 2048
#define BB 256
#define II 64
#define HH 128
#define GG 512   // 4*H
#define NHH 512
#define OO 64

#define OSTRIDE 516   // shorts/row: dword-stride 258 %32 = 2 -> b64 reads at conflict floor

typedef short short8 __attribute__((ext_vector_type(8)));
typedef short short4v __attribute__((ext_vector_type(4)));
typedef float f32x4 __attribute__((ext_vector_type(4)));
typedef unsigned short us4 __attribute__((ext_vector_type(4)));

__device__ __forceinline__ short f2bf(float f) {
    unsigned u = __float_as_uint(f);
    unsigned r = (u + 0x7fffu + ((u >> 16) & 1u)) >> 16;   // RNE
    return (short)r;
}
__device__ __forceinline__ float bf2f(unsigned short s) {
    return __uint_as_float(((unsigned)s) << 16);
}
__device__ __forceinline__ float sigm(float x) {
    return __builtin_amdgcn_rcpf(1.f + __expf(-x));
}
__device__ __forceinline__ float tanh_f(float x) {
    float e = __expf(-2.f * fabsf(x));
    float t = (1.f - e) * __builtin_amdgcn_rcpf(1.f + e);
    return copysignf(t, x);
}
// LDS-only barrier: waits lgkmcnt(0) but NOT vmcnt -> no HBM-store drain per step
__device__ __forceinline__ void sync_lds() {
    __builtin_amdgcn_s_waitcnt(0xC07F);
    __builtin_amdgcn_s_barrier();
}

// ---------- prep: bf16 conversions + fused bias ----------
__global__ void prep_kernel(const float* __restrict__ W_ih,
                            const float* __restrict__ b_ih, const float* __restrict__ b_hh,
                            const float* __restrict__ W1,   const float* __restrict__ W2,
                            short* __restrict__ WihBf, float* __restrict__ biasf,
                            short* __restrict__ W1bf, short* __restrict__ W2bf)
{
    int tid = blockIdx.x * blockDim.x + threadIdx.x;
    int n = gridDim.x * blockDim.x;
    for (int i = tid; i < GG * II; i += n) WihBf[i] = f2bf(W_ih[i]);
    for (int i = tid; i < GG; i += n) biasf[i] = b_ih[i] + b_hh[i];
    for (int i = tid; i < NHH * HH; i += n) W1bf[i] = f2bf(W1[i]);
    for (int i = tid; i < OO * NHH; i += n) W2bf[i] = f2bf(W2[i]);
}

// ---------- xg = x @ W_ih^T + bias, bf16 out, layout [B][T][G] (b-major) ----------
// Block owns 64 consecutive (b,t) rows in b-major flatten: b fixed, t = t0..t0+63.
// Scan then reads xg[b][t][:] as a contiguous 1 KB stream per step.
__global__ __launch_bounds__(256) void xg_gemm2(
    const float* __restrict__ x, const short* __restrict__ WihBf,
    const float* __restrict__ biasf, unsigned short* __restrict__ xg)
{
    const int tid = threadIdx.x, wv = tid >> 6, lane = tid & 63;
    const int lrow = lane & 15, q = lane >> 4;
    const int rb0 = blockIdx.x * 64;
    const int b  = rb0 >> 11;          // T = 2048
    const int t0 = rb0 & (TT - 1);

    f32x4 C[8][4];
    #pragma unroll
    for (int mt = 0; mt < 8; ++mt) {
        float4 bv = *(const float4*)&biasf[wv * 128 + mt * 16 + q * 4];
        f32x4 ci = {bv.x, bv.y, bv.z, bv.w};
        #pragma unroll
        for (int nt = 0; nt < 4; ++nt) C[mt][nt] = ci;
    }
    #pragma unroll
    for (int kt = 0; kt < 2; ++kt) {
        short8 Bx[4];
        #pragma unroll
        for (int nt = 0; nt < 4; ++nt) {
            int t = t0 + nt * 16 + lrow;
            const float* p = x + ((size_t)t * BB + b) * II + kt * 32 + q * 8;
            float4 f0 = *(const float4*)p;
            float4 f1 = *(const float4*)(p + 4);
            short8 bb;
            bb[0] = f2bf(f0.x); bb[1] = f2bf(f0.y); bb[2] = f2bf(f0.z); bb[3] = f2bf(f0.w);
            bb[4] = f2bf(f1.x); bb[5] = f2bf(f1.y); bb[6] = f2bf(f1.z); bb[7] = f2bf(f1.w);
            Bx[nt] = bb;
        }
        #pragma unroll
        for (int mt = 0; mt < 8; ++mt) {
            short8 Aw = *(const short8*)&WihBf[(wv * 128 + mt * 16 + lrow) * II + kt * 32 + q * 8];
            #pragma unroll
            for (int nt = 0; nt < 4; ++nt)
                C[mt][nt] = __builtin_amdgcn_mfma_f32_16x16x32_bf16(Aw, Bx[nt], C[mt][nt], 0, 0, 0);
        }
    }
    #pragma unroll
    for (int mt = 0; mt < 8; ++mt) {
        #pragma unroll
        for (int nt = 0; nt < 4; ++nt) {
            int t = t0 + nt * 16 + lrow;
            us4 us;
            us.x = (unsigned short)f2bf(C[mt][nt][0]);
            us.y = (unsigned short)f2bf(C[mt][nt][1]);
            us.z = (unsigned short)f2bf(C[mt][nt][2]);
            us.w = (unsigned short)f2bf(C[mt][nt][3]);
            *(us4*)&xg[((size_t)b * TT + t) * GG + wv * 128 + mt * 16 + q * 4] = us;
        }
    }
}

// ---------- LSTM scan: 256 blocks x 1 batch row, 8 waves, gate-interleaved MFMA ----------
// USEXG: K=128 (h only, 16 MFMA/wave/step), gate pre-acts seeded from xg[b][t][:] via
// 4 ushort loads/wave (only reg 0 of the seed is a real row), 2-step register prefetch.
// Else: K=192 with in-scan x staging (fallback).
template<bool USEXG>
__global__ __launch_bounds__(512, 2) void lstm_scan7(
    const float* __restrict__ x, const unsigned short* __restrict__ xg,
    const float* __restrict__ W_ih, const float* __restrict__ W_hh,
    const float* __restrict__ b_ih, const float* __restrict__ b_hh,
    unsigned short* __restrict__ hs, float* __restrict__ out_tail)
{
    __shared__ __align__(16) short hbuf[2][HH];
    __shared__ __align__(16) short xbuf[2][II];   // only touched when !USEXG

    constexpr int KT = USEXG ? 4 : 6;
    constexpr int KH = USEXG ? 2 : 3;   // Ca/Cb accumulator split point

    const int tid  = threadIdx.x;
    const int wv   = tid >> 6;            // 8 waves
    const int lane = tid & 63;
    const int lrow = lane & 15;
    const int q    = lane >> 4;
    const int b    = blockIdx.x;          // one batch row per block
    const int col  = wv * 16 + lrow;      // this lane's h-column (lanes<16 only)

    if (tid < 2 * HH) ((short*)hbuf)[tid] = 0;

    // B-frags: gate g, cols [wv*16, wv*16+16), K = [h(128) | x(64 iff !USEXG)]
    short8 Bf[4][KT];
    float biasv[4];
    int colg[4];
    #pragma unroll
    for (int g = 0; g < 4; ++g) {
        int n = g * 128 + wv * 16 + lrow;         // gate pre-act index = W row
        colg[g] = n;
        if (!USEXG) biasv[g] = b_ih[n] + b_hh[n];
        #pragma unroll
        for (int kt = 0; kt < KT; ++kt) {
            const float* p = (kt < 4) ? (W_hh + (size_t)n * HH + kt * 32 + q * 8)
                                      : (W_ih + (size_t)n * II + (kt - 4) * 32 + q * 8);
            float4 f0 = *(const float4*)p;
            float4 f1 = *(const float4*)(p + 4);
            short8 bb;
            bb[0] = f2bf(f0.x); bb[1] = f2bf(f0.y); bb[2] = f2bf(f0.z); bb[3] = f2bf(f0.w);
            bb[4] = f2bf(f1.x); bb[5] = f2bf(f1.y); bb[6] = f2bf(f1.z); bb[7] = f2bf(f1.w);
            Bf[g][kt] = bb;
        }
    }

    // xg prefetch: two 4-ushort register sets alternating by step parity (no rotation movs);
    // each step consumes its set then reloads it for t+2 (load->use gap = 2 steps ~ HBM latency)
    const unsigned short* xgp = USEXG ? (xg + (size_t)b * TT * GG) : nullptr;
    unsigned short xga[4], xgb[4];
    if (USEXG) {
        #pragma unroll
        for (int g = 0; g < 4; ++g) {
            xga[g] = xgp[colg[g]];
            xgb[g] = xgp[GG + colg[g]];
        }
    }

    // x staging (fallback path)
    float xa = 0.f, xb_r = 0.f;
    const float* xp = nullptr;
    if (!USEXG) {
        if (tid < II) {
            xbuf[0][tid] = f2bf(x[(size_t)b * II + tid]);
            xa   = x[(size_t)1 * BB * II + (size_t)b * II + tid];
            xb_r = x[(size_t)2 * BB * II + (size_t)b * II + tid];
        }
        xp = x + (size_t)3 * BB * II + (size_t)b * II + tid;
    }

    float c = 0.f, hlast = 0.f;
    unsigned short* hp = hs + (size_t)b * HH + col;

    __syncthreads();   // full sync once: LDS init visible + startup vmem drained

    auto step = [&](int t, int par, unsigned short (&xgc)[4], float& xreg) {
        const short* hb = hbuf[par];
        // A-frags, broadcast (16 lanes per address -> conflict-free)
        short8 Af[KT];
        #pragma unroll
        for (int kt = 0; kt < 4; ++kt)
            Af[kt] = *(const short8*)&hb[kt * 32 + q * 8];
        if constexpr (!USEXG) {
            const short* xbp = xbuf[par];
            Af[4] = *(const short8*)&xbp[q * 8];
            Af[5] = *(const short8*)&xbp[32 + q * 8];
            if (tid < II) {
                xbuf[par ^ 1][tid] = f2bf(xreg);
                xreg = (t + 3 < TT) ? *xp : 0.f;
                xp += BB * II;
            }
        }

        // C-init: xg seed (only element 0 = row 0 is real) or bias broadcast
        f32x4 Ca[4], Cb[4];
        #pragma unroll
        for (int g = 0; g < 4; ++g) {
            if constexpr (USEXG) {
                f32x4 ci = {bf2f(xgc[g]), 0.f, 0.f, 0.f};
                Ca[g] = ci;
            } else {
                f32x4 ci = {biasv[g], biasv[g], biasv[g], biasv[g]};
                Ca[g] = ci;
            }
            f32x4 z = {0.f, 0.f, 0.f, 0.f};
            Cb[g] = z;
        }
        // prefetch xg for t+2 into the just-consumed regs
        if constexpr (USEXG) {
            if (t + 2 < TT) {
                #pragma unroll
                for (int g = 0; g < 4; ++g)
                    xgc[g] = xgp[(size_t)(t + 2) * GG + colg[g]];
            }
        }

        // gate pre-acts: split accumulators -> 8 chains, latency-pipelined
        #pragma unroll
        for (int kt = 0; kt < KH; ++kt)
            #pragma unroll
            for (int g = 0; g < 4; ++g)
                Ca[g] = __builtin_amdgcn_mfma_f32_16x16x32_bf16(Af[kt], Bf[g][kt], Ca[g], 0, 0, 0);
        #pragma unroll
        for (int kt = KH; kt < KT; ++kt)
            #pragma unroll
            for (int g = 0; g < 4; ++g)
                Cb[g] = __builtin_amdgcn_mfma_f32_16x16x32_bf16(Af[kt], Bf[g][kt], Cb[g], 0, 0, 0);

        // in-register activations: lane l<16 holds {i,f,g,o} of col wv*16+l at reg 0
        if (lane < 16) {
            float gi = Ca[0][0] + Cb[0][0];
            float gf = Ca[1][0] + Cb[1][0];
            float gg = Ca[2][0] + Cb[2][0];
            float go = Ca[3][0] + Cb[3][0];
            c = sigm(gf) * c + sigm(gi) * tanh_f(gg);
            float h = sigm(go) * tanh_f(c);
            hlast = h;
            unsigned short hbb = (unsigned short)f2bf(h);
            hbuf[par ^ 1][col] = (short)hbb;
            *hp = hbb;
        }
        hp += (size_t)BB * HH;
        sync_lds();   // h_{t+1} (and x_{t+1}) visible; single barrier per step
    };

    for (int t = 0; t < TT; t += 2) {
        step(t, 0, xga, xa);
        step(t + 1, 1, xgb, xb_r);
    }

    if (lane < 16) {
        out_tail[(size_t)b * HH + col] = hlast;
        out_tail[(size_t)BB * HH + (size_t)b * HH + col] = c;
    }
}

// ---------- fused head MLP v2: 64 rows/block, fully hoisted A/B frags ----------
__global__ __launch_bounds__(512, 2) void head_mfma2(
    const unsigned short* __restrict__ hs,
    const short* __restrict__ W1bf, const float* __restrict__ b1,
    const short* __restrict__ W2bf, const float* __restrict__ b2,
    float* __restrict__ out)
{
    __shared__ short o1[64 * OSTRIDE];   // 66 KB -> 2 blocks/CU

    const int tid = threadIdx.x, wv = tid >> 6, lane = tid & 63;
    const int lrow = lane & 15, q = lane >> 4;
    const size_t rows0 = (size_t)blockIdx.x * 64;

    // GEMM1: wave wv owns cols [wv*64, wv*64+64); all 4 M-tiles.
    // Hoist ALL frags (16 B + 16 A loads, independent) -> one fill, 64 straight MFMAs.
    short8 B1[4][4];   // [nt][kt]
    #pragma unroll
    for (int nt = 0; nt < 4; ++nt)
        #pragma unroll
        for (int kt = 0; kt < 4; ++kt)
            B1[nt][kt] = *(const short8*)&W1bf[(wv * 64 + nt * 16 + lrow) * HH + kt * 32 + q * 8];
    short8 A1[4][4];   // [mt][kt]
    #pragma unroll
    for (int mt = 0; mt < 4; ++mt)
        #pragma unroll
        for (int kt = 0; kt < 4; ++kt)
            A1[mt][kt] = *(const short8*)(hs + (rows0 + mt * 16 + lrow) * HH + kt * 32 + q * 8);

    #pragma unroll
    for (int mt = 0; mt < 4; ++mt) {
        f32x4 C1[4];
        #pragma unroll
        for (int nt = 0; nt < 4; ++nt) {
            float bv = b1[wv * 64 + nt * 16 + lrow];
            f32x4 ci = {bv, bv, bv, bv};
            C1[nt] = ci;
        }
        #pragma unroll
        for (int kt = 0; kt < 4; ++kt)
            #pragma unroll
            for (int nt = 0; nt < 4; ++nt)
                C1[nt] = __builtin_amdgcn_mfma_f32_16x16x32_bf16(A1[mt][kt], B1[nt][kt], C1[nt], 0, 0, 0);
        #pragma unroll
        for (int nt = 0; nt < 4; ++nt)
            #pragma unroll
            for (int reg = 0; reg < 4; ++reg) {
                float v = C1[nt][reg];
                v = v > 0.f ? v : 0.f;
                o1[(mt * 16 + q * 4 + reg) * OSTRIDE + wv * 64 + nt * 16 + lrow] = f2bf(v);
            }
    }
    __syncthreads();

    // GEMM2: wave -> (mt2 = wv>>1 of 4 M-tiles, nh pair = (wv&1)*2 of 4 N-tiles)
    const int mt2 = wv >> 1;
    const int nh0 = (wv & 1) * 2;
    f32x4 C2a[2], C2b[2];
    #pragma unroll
    for (int j = 0; j < 2; ++j) {
        float bv = b2[(nh0 + j) * 16 + lrow];
        f32x4 ci = {bv, bv, bv, bv};
        C2a[j] = ci;
        f32x4 z = {0.f, 0.f, 0.f, 0.f};
        C2b[j] = z;
    }
    #pragma unroll
    for (int kt = 0; kt < 16; ++kt) {
        int off = (mt2 * 16 + lrow) * OSTRIDE + kt * 32 + q * 8;
        union { short8 v; short4v h[2]; } u;
        u.h[0] = *(const short4v*)&o1[off];
        u.h[1] = *(const short4v*)&o1[off + 4];
        #pragma unroll
        for (int j = 0; j < 2; ++j) {
            short8 Bfr = *(const short8*)&W2bf[((nh0 + j) * 16 + lrow) * NHH + kt * 32 + q * 8];
            if (kt & 1) C2b[j] = __builtin_amdgcn_mfma_f32_16x16x32_bf16(u.v, Bfr, C2b[j], 0, 0, 0);
            else        C2a[j] = __builtin_amdgcn_mfma_f32_16x16x32_bf16(u.v, Bfr, C2a[j], 0, 0, 0);
        }
    }
    #pragma unroll
    for (int j = 0; j < 2; ++j)
        #pragma unroll
        for (int reg = 0; reg < 4; ++reg)
            out[(rows0 + mt2 * 16 + q * 4 + reg) * OO + (nh0 + j) * 16 + lrow] = C2a[j][reg] + C2b[j][reg];
}

extern "C" void kernel_launch(void* const* d_in, const int* in_sizes, int n_in,
                              void* d_out, int out_size, void* d_ws, size_t ws_size,
                              hipStream_t stream)
{
    const float* x    = (const float*)d_in[0];
    const float* W_ih = (const float*)d_in[1];
    const float* W_hh = (const float*)d_in[2];
    const float* b_ih = (const float*)d_in[3];
    const float* b_hh = (const float*)d_in[4];
    const float* W1   = (const float*)d_in[5];
    const float* b1   = (const float*)d_in[6];
    const float* W2   = (const float*)d_in[7];
    const float* b2   = (const float*)d_in[8];
    float* out = (float*)d_out;

    char* ws = (char*)d_ws;
    short* W1bf  = (short*)(ws + 0);                       // 131072
    short* W2bf  = (short*)(ws + 131072);                  // 65536
    short* WihBf = (short*)(ws + 196608);                  // 65536
    float* biasf = (float*)(ws + 262144);                  // 2048
    unsigned short* hs = (unsigned short*)(ws + 264192);   // 134217728
    unsigned short* xgbuf = (unsigned short*)(ws + 134481920);  // 536870912

    const bool fast = ws_size >= 671352832ULL;   // constant per session -> graph-safe

    prep_kernel<<<64, 256, 0, stream>>>(W_ih, b_ih, b_hh, W1, W2, WihBf, biasf, W1bf, W2bf);

    float* tail = out + (size_t)TT * BB * OO;
    if (fast) {
        xg_gemm2<<<(TT * BB) / 64, 256, 0, stream>>>(x, WihBf, biasf, xgbuf);
        lstm_scan7<true><<<BB, 512, 0, stream>>>(x, xgbuf, W_ih, W_hh, b_ih, b_hh, hs, tail);
    } else {
        lstm_scan7<false><<<BB, 512, 0, stream>>>(x, nullptr, W_ih, W_hh, b_ih, b_hh, hs, tail);
    }

    head_mfma2<<<(TT * BB) / 64, 512, 0, stream>>>(hs, W1bf, b1, W2bf, b2, out);
}